// Round 1
// baseline (270.831 us; speedup 1.0000x reference)
//
#include <hip/hip_runtime.h>

// ---- types -----------------------------------------------------------------
typedef __bf16 bf16;
typedef __attribute__((ext_vector_type(8))) __bf16 bf16x8;
typedef __attribute__((ext_vector_type(4))) __bf16 bf16x4;
typedef __attribute__((ext_vector_type(4))) float  f32x4;

static __device__ __forceinline__ f32x4 mfma16(bf16x8 a, bf16x8 b, f32x4 c) {
  return __builtin_amdgcn_mfma_f32_16x16x32_bf16(a, b, c, 0, 0, 0);
}

// Problem constants: B=64, S=1024, XDIM=256, YDIM=128.
// C1 = log2(e)/sqrt(YDIM): p = exp(s/sqrt(128)) = exp2(s*C1)
#define EXP_C1 (1.4426950408889634f / 11.313708498984760f)

// ============================================================================
// Kernel 1: QKV projection.  grid(3, 512), block 256.
//   x: 0->Q, 1->K, 2->V.  y: 128-row m-tile of the flattened [B*S, 256] input.
//   Q,K stored [b][s][128] bf16. V stored transposed VT[b][d][s] bf16
//   (C-fragment regs are 4 consecutive rows=s at fixed col=d -> 8B packed store).
// ============================================================================
__global__ __launch_bounds__(256) void k_qkv(
    const float* __restrict__ q,
    const float* __restrict__ Wq, const float* __restrict__ Wk, const float* __restrict__ Wv,
    const float* __restrict__ bq, const float* __restrict__ bk, const float* __restrict__ bv,
    bf16* __restrict__ Qb, bf16* __restrict__ Kb, bf16* __restrict__ VT)
{
  const int bx = blockIdx.x;
  const int m0 = blockIdx.y * 128;
  const float* W    = (bx == 0) ? Wq : (bx == 1) ? Wk : Wv;
  const float* bias = (bx == 0) ? bq : (bx == 1) ? bk : bv;

  __shared__ bf16 Al[128][72];   // 128 x BK=64, +8 pad (2-way LDS aliasing = free)
  __shared__ bf16 Bl[128][72];

  const int tid  = threadIdx.x;
  const int lane = tid & 63, wave = tid >> 6;
  const int ln = lane & 15, quad = lane >> 4, q8 = quad * 8;
  const int wr = wave >> 1, wc = wave & 1;          // 2x2 waves, 64x64 per wave

  f32x4 acc[4][4] = {};

  const int c4 = tid & 15, r0 = tid >> 4;
  for (int kb = 0; kb < 256; kb += 64) {
    __syncthreads();
    // stage A (q rows, fp32 -> bf16) and B (W rows) : 128x64 each
    for (int p = 0; p < 8; ++p) {
      int r = r0 + p * 16;
      float4 va = *(const float4*)(q + (size_t)(m0 + r) * 256 + kb + c4 * 4);
      bf16x4 oa = { (bf16)va.x, (bf16)va.y, (bf16)va.z, (bf16)va.w };
      *(bf16x4*)&Al[r][c4 * 4] = oa;
      float4 vb = *(const float4*)(W + (size_t)r * 256 + kb + c4 * 4);
      bf16x4 ob = { (bf16)vb.x, (bf16)vb.y, (bf16)vb.z, (bf16)vb.w };
      *(bf16x4*)&Bl[r][c4 * 4] = ob;
    }
    __syncthreads();
    for (int ks = 0; ks < 64; ks += 32) {
      bf16x8 af[4], bfr[4];
      for (int i = 0; i < 4; ++i) af[i]  = *(const bf16x8*)&Al[wr * 64 + i * 16 + ln][ks + q8];
      for (int j = 0; j < 4; ++j) bfr[j] = *(const bf16x8*)&Bl[wc * 64 + j * 16 + ln][ks + q8];
      for (int i = 0; i < 4; ++i)
        for (int j = 0; j < 4; ++j)
          acc[i][j] = mfma16(af[i], bfr[j], acc[i][j]);
    }
  }

  const int b = m0 >> 10, s0 = m0 & 1023;           // 128 | 1024: whole tile in one batch
  if (bx < 2) {
    bf16* dst = ((bx == 0) ? Qb : Kb) + ((size_t)b * 1024 + s0) * 128;
    for (int j = 0; j < 4; ++j) {
      int d = wc * 64 + j * 16 + ln;
      float bb = bias[d];
      for (int i = 0; i < 4; ++i) {
        int rbase = wr * 64 + i * 16 + quad * 4;
        for (int r = 0; r < 4; ++r)
          dst[(size_t)(rbase + r) * 128 + d] = (bf16)(acc[i][j][r] + bb);
      }
    }
  } else {
    for (int j = 0; j < 4; ++j) {
      int d = wc * 64 + j * 16 + ln;
      float bb = bias[d];
      bf16* dst = VT + ((size_t)b * 128 + d) * 1024 + s0;
      for (int i = 0; i < 4; ++i) {
        int sb = wr * 64 + i * 16 + quad * 4;
        bf16x4 o = { (bf16)(acc[i][j][0] + bb), (bf16)(acc[i][j][1] + bb),
                     (bf16)(acc[i][j][2] + bb), (bf16)(acc[i][j][3] + bb) };
        *(bf16x4*)(dst + sb) = o;
      }
    }
  }
}

// ============================================================================
// Kernel 2: column stats.  grid(8 ktile, 64 b), block 256.
//   l'[k] = sum_q exp(s[q,k]/scale) for the block's 128 k-columns (loop q-tiles),
//   then scale VT rows in place: Vc[d][k] = V[d][k] / l'[k].
//   No max subtraction: s ~ N(0,1), exp stays tiny vs fp32 range.
// ============================================================================
__global__ __launch_bounds__(256) void k_stats(
    const bf16* __restrict__ Qb, const bf16* __restrict__ Kb, bf16* __restrict__ VT)
{
  const int kt = blockIdx.x, b = blockIdx.y;
  __shared__ bf16 Kl[128][136];
  __shared__ bf16 Ql[128][136];
  __shared__ float red[2][128];
  __shared__ float inv[128];

  const int tid  = threadIdx.x;
  const int lane = tid & 63, wave = tid >> 6;
  const int ln = lane & 15, q8 = (lane >> 4) * 8;
  const int wr = wave >> 1, wc = wave & 1;          // 64(q) x 64(k) per wave

  { // stage K-tile once: rows k, 128 d each
    int r = tid >> 1, h = tid & 1;
    const uint4* src = (const uint4*)(Kb + ((size_t)b * 1024 + kt * 128 + r) * 128 + h * 64);
    for (int i = 0; i < 8; ++i) *(uint4*)&Kl[r][h * 64 + i * 8] = src[i];
  }

  float cs[4] = {0.f, 0.f, 0.f, 0.f};

  for (int qt = 0; qt < 8; ++qt) {
    __syncthreads();
    {
      int r = tid >> 1, h = tid & 1;
      const uint4* src = (const uint4*)(Qb + ((size_t)b * 1024 + qt * 128 + r) * 128 + h * 64);
      for (int i = 0; i < 8; ++i) *(uint4*)&Ql[r][h * 64 + i * 8] = src[i];
    }
    __syncthreads();
    f32x4 acc[4][4] = {};
    for (int ks = 0; ks < 128; ks += 32) {
      bf16x8 af[4], bfr[4];
      for (int i = 0; i < 4; ++i) af[i]  = *(const bf16x8*)&Ql[wr * 64 + i * 16 + ln][ks + q8];
      for (int j = 0; j < 4; ++j) bfr[j] = *(const bf16x8*)&Kl[wc * 64 + j * 16 + ln][ks + q8];
      for (int i = 0; i < 4; ++i)
        for (int j = 0; j < 4; ++j)
          acc[i][j] = mfma16(af[i], bfr[j], acc[i][j]);
    }
    for (int j = 0; j < 4; ++j)
      for (int i = 0; i < 4; ++i)
        for (int r = 0; r < 4; ++r)
          cs[j] += exp2f(acc[i][j][r] * EXP_C1);
  }

  // per-column totals: quads hold disjoint q-rows of the same column
  for (int j = 0; j < 4; ++j) {
    cs[j] += __shfl_xor(cs[j], 16, 64);
    cs[j] += __shfl_xor(cs[j], 32, 64);
  }
  if (lane < 16)
    for (int j = 0; j < 4; ++j)
      red[wr][wc * 64 + j * 16 + lane] = cs[j];
  __syncthreads();
  if (tid < 128) inv[tid] = 1.0f / (red[0][tid] + red[1][tid]);
  __syncthreads();

  { // scale VT in place (rows d, our 128 k-columns are contiguous per row)
    int d = tid >> 1, h = tid & 1;
    bf16* p = VT + ((size_t)b * 128 + d) * 1024 + kt * 128 + h * 64;
    for (int i = 0; i < 8; ++i) {
      bf16x8 v = *(bf16x8*)(p + i * 8);
      for (int e = 0; e < 8; ++e)
        v[e] = (bf16)((float)v[e] * inv[h * 64 + i * 8 + e]);
      *(bf16x8*)(p + i * 8) = v;
    }
  }
}

// ============================================================================
// Kernel 3: fused QK^T -> exp -> P@Vc -> running max over q.
//   grid(8 qtile, 64 b), block 512 = 8 waves (2 q x 4 col), wave tile 64x32.
//   No softmax rescaling needed (Vc pre-normalized). P round-trips LDS to get
//   A-operand layout for the PV MFMA. Partial q-max per (b,qtile) -> ws.
// ============================================================================
__global__ __launch_bounds__(512) void k_attn(
    const bf16* __restrict__ Qb, const bf16* __restrict__ Kb, const bf16* __restrict__ VT,
    float* __restrict__ Opart)
{
  const int qt = blockIdx.x, b = blockIdx.y;
  __shared__ bf16 Ql[128][136];
  __shared__ bf16 Kl[128][136];
  __shared__ bf16 Vl[128][136];   // Vc^T tile: rows d, cols k
  __shared__ bf16 Pl[128][136];   // rows q, cols k
  __shared__ float redm[2][128];

  const int tid  = threadIdx.x;
  const int lane = tid & 63, wave = tid >> 6;
  const int ln = lane & 15, quad = lane >> 4, q8 = quad * 8;
  const int wr = wave >> 2, wc = wave & 3;          // 2x4 waves

  { // stage Q-tile once
    int r = tid >> 2, qd = tid & 3;
    const uint4* src = (const uint4*)(Qb + ((size_t)b * 1024 + qt * 128 + r) * 128 + qd * 32);
    uint4* dst = (uint4*)&Ql[r][qd * 32];
    for (int i = 0; i < 4; ++i) dst[i] = src[i];
  }

  f32x4 oacc[4][2] = {};

  for (int ktile = 0; ktile < 8; ++ktile) {
    __syncthreads();
    { // stage K-tile [k][d] and Vc^T-tile [d][k]
      int r = tid >> 2, qd = tid & 3;
      const uint4* srck = (const uint4*)(Kb + ((size_t)b * 1024 + ktile * 128 + r) * 128 + qd * 32);
      uint4* dstk = (uint4*)&Kl[r][qd * 32];
      for (int i = 0; i < 4; ++i) dstk[i] = srck[i];
      const uint4* srcv = (const uint4*)(VT + ((size_t)b * 128 + r) * 1024 + ktile * 128 + qd * 32);
      uint4* dstv = (uint4*)&Vl[r][qd * 32];
      for (int i = 0; i < 4; ++i) dstv[i] = srcv[i];
    }
    __syncthreads();

    // s = Q K^T  (GEMM-K = d = 128)
    f32x4 sacc[4][2] = {};
    for (int ks = 0; ks < 128; ks += 32) {
      bf16x8 af[4], bfr[2];
      for (int i = 0; i < 4; ++i) af[i]  = *(const bf16x8*)&Ql[wr * 64 + i * 16 + ln][ks + q8];
      for (int j = 0; j < 2; ++j) bfr[j] = *(const bf16x8*)&Kl[wc * 32 + j * 16 + ln][ks + q8];
      for (int i = 0; i < 4; ++i)
        for (int j = 0; j < 2; ++j)
          sacc[i][j] = mfma16(af[i], bfr[j], sacc[i][j]);
    }
    // p = exp(s/scale) -> LDS in A-operand layout [q][k]
    for (int i = 0; i < 4; ++i)
      for (int j = 0; j < 2; ++j) {
        int col = wc * 32 + j * 16 + ln;
        int rbase = wr * 64 + i * 16 + quad * 4;
        for (int r = 0; r < 4; ++r)
          Pl[rbase + r][col] = (bf16)exp2f(sacc[i][j][r] * EXP_C1);
      }
    __syncthreads();
    // out += P @ Vc  (GEMM-K = k = 128)
    for (int ks = 0; ks < 128; ks += 32) {
      bf16x8 af[4], bfr[2];
      for (int i = 0; i < 4; ++i) af[i]  = *(const bf16x8*)&Pl[wr * 64 + i * 16 + ln][ks + q8];
      for (int j = 0; j < 2; ++j) bfr[j] = *(const bf16x8*)&Vl[wc * 32 + j * 16 + ln][ks + q8];
      for (int i = 0; i < 4; ++i)
        for (int j = 0; j < 2; ++j)
          oacc[i][j] = mfma16(af[i], bfr[j], oacc[i][j]);
    }
  }

  // max over this tile's 128 q rows, per output column d
  for (int j = 0; j < 2; ++j) {
    float m = -3.4e38f;
    for (int i = 0; i < 4; ++i)
      for (int r = 0; r < 4; ++r)
        m = fmaxf(m, oacc[i][j][r]);
    m = fmaxf(m, __shfl_xor(m, 16, 64));
    m = fmaxf(m, __shfl_xor(m, 32, 64));
    if (lane < 16) redm[wr][wc * 32 + j * 16 + lane] = m;
  }
  __syncthreads();
  if (tid < 128)
    Opart[((size_t)b * 8 + qt) * 128 + tid] = fmaxf(redm[0][tid], redm[1][tid]);
}

// ============================================================================
// Kernel 4: final 8-way max over q-tiles -> d_out [64,128] fp32
// ============================================================================
__global__ __launch_bounds__(256) void k_final(
    const float* __restrict__ Opart, float* __restrict__ out)
{
  int t = blockIdx.x * 256 + threadIdx.x;           // 8192 outputs
  int b = t >> 7, d = t & 127;
  const float* p = Opart + (size_t)b * 8 * 128 + d;
  float m = p[0];
  for (int i = 1; i < 8; ++i) m = fmaxf(m, p[(size_t)i * 128]);
  out[t] = m;
}

// ============================================================================
extern "C" void kernel_launch(void* const* d_in, const int* in_sizes, int n_in,
                              void* d_out, int out_size, void* d_ws, size_t ws_size,
                              hipStream_t stream) {
  const float* q  = (const float*)d_in[0];
  const float* Wq = (const float*)d_in[1];
  const float* bq = (const float*)d_in[2];
  const float* Wk = (const float*)d_in[3];
  const float* bk = (const float*)d_in[4];
  const float* Wv = (const float*)d_in[5];
  const float* bv = (const float*)d_in[6];
  float* out = (float*)d_out;

  char* ws = (char*)d_ws;
  bf16*  Qb    = (bf16*)(ws);                     // 16 MB  [64][1024][128]
  bf16*  Kb    = (bf16*)(ws + (16u << 20));       // 16 MB  [64][1024][128]
  bf16*  VT    = (bf16*)(ws + (32u << 20));       // 16 MB  [64][128][1024] (transposed)
  float* Opart = (float*)(ws + (48u << 20));      // 256 KB [64][8][128]

  k_qkv  <<<dim3(3, 512), 256, 0, stream>>>(q, Wq, Wk, Wv, bq, bk, bv, Qb, Kb, VT);
  k_stats<<<dim3(8, 64),  256, 0, stream>>>(Qb, Kb, VT);
  k_attn <<<dim3(8, 64),  512, 0, stream>>>(Qb, Kb, VT, Opart);
  k_final<<<32, 256, 0, stream>>>(Opart, out);
}

// Round 2
// 217.975 us; speedup vs baseline: 1.2425x; 1.2425x over previous
//
#include <hip/hip_runtime.h>

// ---- types -----------------------------------------------------------------
typedef __bf16 bf16;
typedef __attribute__((ext_vector_type(8))) __bf16 bf16x8;
typedef __attribute__((ext_vector_type(4))) __bf16 bf16x4;
typedef __attribute__((ext_vector_type(4))) float  f32x4;

static __device__ __forceinline__ f32x4 mfma16(bf16x8 a, bf16x8 b, f32x4 c) {
  return __builtin_amdgcn_mfma_f32_16x16x32_bf16(a, b, c, 0, 0, 0);
}

// exp(s/sqrt(128)) = exp2(s * C1)
#define EXP_C1 (1.4426950408889634f / 11.313708498984760f)

// async global->LDS, 16B per lane. LDS dst must be wave-uniform.
typedef const __attribute__((address_space(1))) unsigned int gas_u32;
typedef __attribute__((address_space(3))) unsigned int las_u32;
#define GLDS16(gp, lp) __builtin_amdgcn_global_load_lds((gas_u32*)(gp), (las_u32*)(lp), 16, 0, 0)

// Granule-major tile format (128 rows x 128 cols bf16, 32KB):
//   elem_off(r,c) = (c>>3)*1024 + r*8 + (c&7)
// -> fragment reads (16 rows x 8 contiguous cols) are 16B units at 16B row
//    stride: bank-balanced, and tiles DMA linearly via global_load_lds.

// ============================================================================
// Kernel 1: QKV projection. grid(512), block 256. One block = 128 rows of the
// flattened [B*S, 256] input; loops Q,K,V projections reusing the staged
// A-tile (q read ONCE). LDS A/B tiles are XOR-swizzled (v = g ^ (r&15)) so
// both the fp32->bf16 staging writes and the fragment reads are bank-balanced.
// Outputs: Qb,Kb granule-major [b][s_tile]; VT granule-major [b][k_tile] with
// row=d, col=s (i.e. V transposed), written straight from the C-fragment.
// ============================================================================
__global__ __launch_bounds__(256) void k_qkv(
    const float* __restrict__ q,
    const float* __restrict__ Wq, const float* __restrict__ Wk, const float* __restrict__ Wv,
    const float* __restrict__ bq, const float* __restrict__ bk, const float* __restrict__ bv,
    bf16* __restrict__ Qb, bf16* __restrict__ Kb, bf16* __restrict__ VT)
{
  __shared__ bf16 Al[32768];   // 128 x 256, XOR-swizzled, 64KB
  __shared__ bf16 Bl[32768];   // 128 x 256, XOR-swizzled, 64KB

  const int tid = threadIdx.x;
  const int lane = tid & 63, wave = tid >> 6;
  const int ln = lane & 15, quad = lane >> 4;
  const int wr = wave >> 1, wc = wave & 1;        // 2x2 waves, 64x64 each
  const int m0 = blockIdx.x * 128;

  { // stage A: q tile fp32 -> bf16 (coalesced 1KB/wave-inst)
    const float* src = q + (size_t)m0 * 256;
    for (int it = 0; it < 32; ++it) {
      int f = it * 1024 + tid * 4;
      int r = f >> 8, c = f & 255;
      float4 v4 = *(const float4*)(src + f);
      int g = c >> 3;
      int vv = (g & 16) | ((g & 15) ^ (r & 15));
      bf16x4 o = { (bf16)v4.x, (bf16)v4.y, (bf16)v4.z, (bf16)v4.w };
      *(bf16x4*)&Al[r * 256 + vv * 8 + (c & 7)] = o;
    }
  }

  const int b = m0 >> 10, st = (m0 & 1023) >> 7;
  const size_t tbase = ((size_t)b * 8 + st) * 16384;

  for (int p = 0; p < 3; ++p) {
    const float* W    = p == 0 ? Wq : p == 1 ? Wk : Wv;
    const float* bias = p == 0 ? bq : p == 1 ? bk : bv;
    __syncthreads();                 // prev MFMA done with Bl (A staged, p=0)
    for (int it = 0; it < 32; ++it) {
      int f = it * 1024 + tid * 4;
      int r = f >> 8, c = f & 255;
      float4 v4 = *(const float4*)(W + f);
      int g = c >> 3;
      int vv = (g & 16) | ((g & 15) ^ (r & 15));
      bf16x4 o = { (bf16)v4.x, (bf16)v4.y, (bf16)v4.z, (bf16)v4.w };
      *(bf16x4*)&Bl[r * 256 + vv * 8 + (c & 7)] = o;
    }
    __syncthreads();

    f32x4 acc[4][4] = {};
    for (int ks = 0; ks < 256; ks += 32) {
      int g = (ks >> 3) + quad;
      bf16x8 af[4], bfr[4];
      for (int i = 0; i < 4; ++i) {
        int vv = (g & 16) | ((g & 15) ^ ln);
        af[i] = *(const bf16x8*)&Al[(wr * 64 + i * 16 + ln) * 256 + vv * 8];
      }
      for (int j = 0; j < 4; ++j) {
        int vv = (g & 16) | ((g & 15) ^ ln);
        bfr[j] = *(const bf16x8*)&Bl[(wc * 64 + j * 16 + ln) * 256 + vv * 8];
      }
      for (int i = 0; i < 4; ++i)
        for (int j = 0; j < 4; ++j)
          acc[i][j] = mfma16(af[i], bfr[j], acc[i][j]);
    }

    if (p < 2) {                     // Q,K: granule-major, row=s, col=d
      bf16* dst = (p == 0 ? Qb : Kb) + tbase;
      for (int j = 0; j < 4; ++j) {
        int d = wc * 64 + j * 16 + ln;
        float bb = bias[d];
        size_t gcol = (size_t)(d >> 3) * 1024 + (d & 7);
        for (int i = 0; i < 4; ++i) {
          int rbase = wr * 64 + i * 16 + quad * 4;
          for (int rr = 0; rr < 4; ++rr)
            dst[gcol + (size_t)(rbase + rr) * 8] = (bf16)(acc[i][j][rr] + bb);
        }
      }
    } else {                         // V: granule-major, row=d, col=s (V^T)
      bf16* dst = VT + tbase;
      for (int j = 0; j < 4; ++j) {
        int d = wc * 64 + j * 16 + ln;
        float bb = bias[d];
        for (int i = 0; i < 4; ++i) {
          int s = wr * 64 + i * 16 + quad * 4;
          bf16x4 o = { (bf16)(acc[i][j][0] + bb), (bf16)(acc[i][j][1] + bb),
                       (bf16)(acc[i][j][2] + bb), (bf16)(acc[i][j][3] + bb) };
          *(bf16x4*)&dst[(size_t)(s >> 3) * 1024 + (size_t)d * 8 + (s & 7)] = o;
        }
      }
    }
  }
}

// ============================================================================
// Kernel 2: column stats + V scaling. grid(8 kt, 64 b), block 256 (2x2 waves).
//   l'[k] = sum_q exp2(s*C1); then VT tile kt scaled in place: Vc = V / l'.
//   K-tile DMA'd once, Q-tiles DMA'd per iteration (global_load_lds x16B).
//   LDS 66.5KB -> 2 blocks/CU.
// ============================================================================
__global__ __launch_bounds__(256) void k_stats(
    const bf16* __restrict__ Qb, const bf16* __restrict__ Kb, bf16* __restrict__ VT)
{
  __shared__ char smem[68096];
  bf16* Kl  = (bf16*)smem;                      // [16 gd][128 k][8]
  bf16* Ql  = (bf16*)(smem + 32768);            // [16 gd][128 q][8]
  float* red = (float*)(smem + 65536);          // [2][128]
  float* inv = (float*)(smem + 66560);          // [128]

  const int kt = blockIdx.x, b = blockIdx.y;
  const int tid = threadIdx.x, lane = tid & 63, wave = tid >> 6;
  const int ln = lane & 15, quad = lane >> 4;
  const int wr = wave >> 1, wc = wave & 1;

  const char* kb_tile = (const char*)(Kb + ((size_t)b * 8 + kt) * 16384);
  for (int ch = wave; ch < 32; ch += 4)
    GLDS16(kb_tile + ch * 1024 + lane * 16, (char*)Kl + ch * 1024);

  float cs[4] = {0.f, 0.f, 0.f, 0.f};

  for (int qt = 0; qt < 8; ++qt) {
    if (qt) __syncthreads();                    // prev MFMA done with Ql
    const char* qb_tile = (const char*)(Qb + ((size_t)b * 8 + qt) * 16384);
    for (int ch = wave; ch < 32; ch += 4)
      GLDS16(qb_tile + ch * 1024 + lane * 16, (char*)Ql + ch * 1024);
    __syncthreads();                            // DMA complete (incl. K @qt=0)

    f32x4 acc[4][4] = {};
    for (int ks = 0; ks < 128; ks += 32) {
      int g = (ks >> 3) + quad;
      bf16x8 af[4], bfr[4];
      for (int i = 0; i < 4; ++i) af[i]  = *(const bf16x8*)&Ql[g * 1024 + (wr * 64 + i * 16 + ln) * 8];
      for (int j = 0; j < 4; ++j) bfr[j] = *(const bf16x8*)&Kl[g * 1024 + (wc * 64 + j * 16 + ln) * 8];
      for (int i = 0; i < 4; ++i)
        for (int j = 0; j < 4; ++j)
          acc[i][j] = mfma16(af[i], bfr[j], acc[i][j]);
    }
    for (int j = 0; j < 4; ++j)
      for (int i = 0; i < 4; ++i)
        for (int rr = 0; rr < 4; ++rr)
          cs[j] += exp2f(acc[i][j][rr] * EXP_C1);
  }

  for (int j = 0; j < 4; ++j) {
    cs[j] += __shfl_xor(cs[j], 16, 64);
    cs[j] += __shfl_xor(cs[j], 32, 64);
  }
  __syncthreads();
  if (lane < 16)
    for (int j = 0; j < 4; ++j)
      red[wr * 128 + wc * 64 + j * 16 + lane] = cs[j];
  __syncthreads();
  if (tid < 128) inv[tid] = 1.0f / (red[tid] + red[128 + tid]);
  __syncthreads();

  { // scale VT tile in place: element (row=d, col-granule g, e): col = g*8+e
    bf16* vt_tile = VT + ((size_t)b * 8 + kt) * 16384;
    int d  = (tid & 63) + (wave & 1) * 64;
    int g0 = (wave >> 1) * 8;
    for (int gg = 0; gg < 8; ++gg) {
      int g = g0 + gg;
      bf16x8 v = *(bf16x8*)&vt_tile[(size_t)g * 1024 + (size_t)d * 8];
      for (int e = 0; e < 8; ++e)
        v[e] = (bf16)((float)v[e] * inv[g * 8 + e]);
      *(bf16x8*)&vt_tile[(size_t)g * 1024 + (size_t)d * 8] = v;
    }
  }
}

// ============================================================================
// Kernel 3: fused QK^T -> exp -> P@Vc -> running max. grid(16 qt, 64 b),
// block 256 (4 waves). q-tile 64, k-tile 64. Q fragments in REGISTERS
// (loaded once from granule-major Qb). LDS = Kl 16K + Vl 16K + Pl 8K = 40KB
// -> 3-4 blocks/CU so stage/exp barriers overlap other blocks' MFMA.
// ============================================================================
__global__ __launch_bounds__(256, 3) void k_attn(
    const bf16* __restrict__ Qb, const bf16* __restrict__ Kb, const bf16* __restrict__ VT,
    float* __restrict__ Opart)
{
  __shared__ char smem[40960];
  bf16* Kl = (bf16*)smem;              // [16 gd][64 k][8]   16KB
  bf16* Vl = (bf16*)(smem + 16384);    // [8 gs][128 d][8]   16KB
  bf16* Pl = (bf16*)(smem + 32768);    // [8 gk][64 q][8]     8KB
  float* redm = (float*)(smem + 32768);// reused after last PV

  const int qt = blockIdx.x, b = blockIdx.y;
  const int tid = threadIdx.x, lane = tid & 63, wave = tid >> 6;
  const int ln = lane & 15, quad = lane >> 4;
  const int wr = wave >> 1, wc = wave & 1;   // QK: 32q x 32k; PV: 32q x 64d

  bf16x8 aq[2][4];
  {
    const char* qtile = (const char*)(Qb + ((size_t)b * 8 + (qt >> 1)) * 16384);
    int rbase = (qt & 1) * 64 + wr * 32 + ln;
    for (int i = 0; i < 2; ++i)
      for (int kk = 0; kk < 4; ++kk)
        aq[i][kk] = *(const bf16x8*)(qtile + (size_t)(kk * 4 + quad) * 2048 + (size_t)(rbase + i * 16) * 16);
  }

  f32x4 oacc[2][4] = {};

  for (int ktile = 0; ktile < 16; ++ktile) {
    __syncthreads();                   // prev PV done with Kl/Vl/Pl
    {
      const char* kb_t = (const char*)(Kb + ((size_t)b * 8 + (ktile >> 1)) * 16384) + (ktile & 1) * 1024;
      for (int ch = wave; ch < 16; ch += 4)
        GLDS16(kb_t + ch * 2048 + lane * 16, (char*)Kl + ch * 1024);
      const char* vt_t = (const char*)(VT + ((size_t)b * 8 + (ktile >> 1)) * 16384) + (ktile & 1) * 16384;
      for (int ch = wave; ch < 16; ch += 4)
        GLDS16(vt_t + ch * 1024 + lane * 16, (char*)Vl + ch * 1024);
    }
    __syncthreads();                   // DMA visible

    // S = Q K^T (K-dim = d = 128), per wave 32q x 32k
    f32x4 sacc[2][2] = {};
    for (int ks = 0; ks < 128; ks += 32) {
      int g = (ks >> 3) + quad;
      bf16x8 bfr[2];
      for (int j = 0; j < 2; ++j) bfr[j] = *(const bf16x8*)&Kl[g * 512 + (wc * 32 + j * 16 + ln) * 8];
      for (int i = 0; i < 2; ++i)
        for (int j = 0; j < 2; ++j)
          sacc[i][j] = mfma16(aq[i][ks >> 5], bfr[j], sacc[i][j]);
    }
    // P = exp2(S*C1) -> Pl (granule-major: rows q, cols k)
    for (int i = 0; i < 2; ++i)
      for (int j = 0; j < 2; ++j) {
        int k = wc * 32 + j * 16 + ln;
        int qrow = wr * 32 + i * 16 + quad * 4;
        bf16* pp = &Pl[(k >> 3) * 512 + (k & 7)];
        for (int rr = 0; rr < 4; ++rr)
          pp[(qrow + rr) * 8] = (bf16)exp2f(sacc[i][j][rr] * EXP_C1);
      }
    __syncthreads();
    // O += P @ Vc (K-dim = k = 64), per wave 32q x 64d
    for (int ks = 0; ks < 64; ks += 32) {
      int g = (ks >> 3) + quad;
      bf16x8 af[2], bfr[4];
      for (int i = 0; i < 2; ++i) af[i]  = *(const bf16x8*)&Pl[g * 512 + (wr * 32 + i * 16 + ln) * 8];
      for (int j = 0; j < 4; ++j) bfr[j] = *(const bf16x8*)&Vl[g * 1024 + (wc * 64 + j * 16 + ln) * 8];
      for (int i = 0; i < 2; ++i)
        for (int j = 0; j < 4; ++j)
          oacc[i][j] = mfma16(af[i], bfr[j], oacc[i][j]);
    }
  }

  __syncthreads();                     // done with Pl; reuse as redm
  for (int j = 0; j < 4; ++j) {
    float m = -3.4e38f;
    for (int i = 0; i < 2; ++i)
      for (int rr = 0; rr < 4; ++rr)
        m = fmaxf(m, oacc[i][j][rr]);
    m = fmaxf(m, __shfl_xor(m, 16, 64));
    m = fmaxf(m, __shfl_xor(m, 32, 64));
    if (lane < 16) redm[wr * 128 + wc * 64 + j * 16 + lane] = m;
  }
  __syncthreads();
  if (tid < 128)
    Opart[((size_t)b * 16 + qt) * 128 + tid] = fmaxf(redm[tid], redm[128 + tid]);
}

// ============================================================================
// Kernel 4: final 16-way max over q-tiles -> d_out [64,128] fp32
// ============================================================================
__global__ __launch_bounds__(256) void k_final(
    const float* __restrict__ Opart, float* __restrict__ out)
{
  int t = blockIdx.x * 256 + threadIdx.x;       // 8192 outputs
  int b = t >> 7, d = t & 127;
  const float* p = Opart + (size_t)b * 2048 + d;
  float m = p[0];
  for (int i = 1; i < 16; ++i) m = fmaxf(m, p[(size_t)i * 128]);
  out[t] = m;
}

// ============================================================================
extern "C" void kernel_launch(void* const* d_in, const int* in_sizes, int n_in,
                              void* d_out, int out_size, void* d_ws, size_t ws_size,
                              hipStream_t stream) {
  const float* q  = (const float*)d_in[0];
  const float* Wq = (const float*)d_in[1];
  const float* bq = (const float*)d_in[2];
  const float* Wk = (const float*)d_in[3];
  const float* bk = (const float*)d_in[4];
  const float* Wv = (const float*)d_in[5];
  const float* bv = (const float*)d_in[6];
  float* out = (float*)d_out;

  char* ws = (char*)d_ws;
  bf16*  Qb    = (bf16*)(ws);                   // 16 MB  granule-major tiles
  bf16*  Kb    = (bf16*)(ws + (16u << 20));     // 16 MB
  bf16*  VT    = (bf16*)(ws + (32u << 20));     // 16 MB  (V^T tiles)
  float* Opart = (float*)(ws + (48u << 20));    // 512 KB [64][16][128]

  k_qkv  <<<dim3(512),    256, 0, stream>>>(q, Wq, Wk, Wv, bq, bk, bv, Qb, Kb, VT);
  k_stats<<<dim3(8, 64),  256, 0, stream>>>(Qb, Kb, VT);
  k_attn <<<dim3(16, 64), 256, 0, stream>>>(Qb, Kb, VT, Opart);
  k_final<<<32, 256, 0, stream>>>(Opart, out);
}